// Round 5
// baseline (733.489 us; speedup 1.0000x reference)
//
#include <hip/hip_runtime.h>
#include <cmath>

// ConvLSTM2D forward, bf16 MFMA implicit GEMM, R10: slice-per-wave shared-A blocks.
// B=8, T=16, H=W=96, Cin=8, F=64 (4F=256 gates), 3x3 SAME, 16 sequential steps.
// Per step GEMM: M=73728, N=256, K=672 (21 K-steps of 32: 18 h + 3 packed x).
// R9 post-mortem: acc[6][4]=96 AGPRs + 84 VGPRs = 180 > 170 -> only 2 waves/SIMD
// (launch_bounds(256,3) unsatisfiable); all-global A added exposed latency.
// R10: block = ONE spatial tile (6 rows x 16 cols, M=96) x 4 slices (wave=slice).
//  - grid 6x16x8 = 768 = exactly 3 blocks/CU: one scheduling round, no tail.
//  - A staged ONCE in LDS (shared by all 4 waves), ring-6 register window;
//    24 MFMA/step/wave (466 SIMD-cyc) per 4 B-loads (2x R8's latency cover).
//  - same-SIMD waves = same slice -> B slab stream L1-resident.
//  - reg budget: 96 acc(AGPR) + 24 ring + 16 B + addr ~= 165 <= 168 -> 3/SIMD.

#define HTOT 96
#define WTOT 96
#define CINX 8
#define FF   64
#define G4   256
#define BB   8
#define TT   16
#define NPOS (BB*HTOT*WTOT)        // 73728 global positions
#define PSTR 1160                  // padded ushorts per h-plane (144*8 + 8 pad)

typedef __attribute__((ext_vector_type(8))) short short8;   // 8 bf16 = 4 VGPRs
typedef __attribute__((ext_vector_type(4))) float floatx4;

union U16 { uint4 u; short8 s; };

__device__ __forceinline__ float hsig(float z) {
    return fminf(fmaxf(0.2f * z + 0.5f, 0.f), 1.f);
}

__device__ __forceinline__ float ftanh(float x) {
    float e = __expf(-2.f * fabsf(x));
    float t = (1.f - e) / (1.f + e);
    return copysignf(t, x);
}

__device__ __forceinline__ ushort f2bf(float f) {            // RNE fp32->bf16
    unsigned u = __float_as_uint(f);
    u = (u + 0x7fff + ((u >> 16) & 1)) >> 16;
    return (ushort)u;
}

// async 16B global->LDS; global src per-lane, LDS dest = uniform base + lane*16
__device__ __forceinline__ void async16(const void* g, void* l) {
    __builtin_amdgcn_global_load_lds(
        (const __attribute__((address_space(1))) void*)g,
        (__attribute__((address_space(3))) void*)l, 16, 0, 0);
}

// ---- prep: x fp32 -> bf16 (all T at once), layout [b,t,y,x,8] ----
__global__ __launch_bounds__(256) void conv_x_bf16(const float* __restrict__ x,
                                                   ushort* __restrict__ xbf, int n4) {
    int i = blockIdx.x * 256 + threadIdx.x;
    if (i >= n4) return;
    float4 v = ((const float4*)x)[i];
    ushort4 o;
    o.x = f2bf(v.x); o.y = f2bf(v.y); o.z = f2bf(v.z); o.w = f2bf(v.w);
    ((ushort4*)xbf)[i] = o;
}

// ---- prep: weights -> per-slice slab stream, slab s order = dx*6 + kh*3 + dy ----
// Bp[(slice*21+s)*256 + g*64 + lane] (16B units); lane(q,col) holds B rows q*8..q*8+7
__global__ __launch_bounds__(256) void prep_w(const float* __restrict__ Wx,
                                              const float* __restrict__ Wh,
                                              ushort* __restrict__ Bp) {
    int idx = blockIdx.x * 256 + threadIdx.x;
    if (idx >= 4 * 21 * 256) return;                 // 21504
    int lane = idx & 63;
    int g = (idx >> 6) & 3;
    int rest = idx >> 8;                             // slice*21 + s
    int s = rest % 21, slice = rest / 21;
    int q = lane >> 4, col = lane & 15;
    int n = g * 64 + slice * 16 + col;
    ushort o[8];
    if (s < 18) {
        int dxw = s / 6, rem = s - 6 * dxw;
        int khw = rem / 3, dyw = rem - 3 * khw;
        int tap = dyw * 3 + dxw;
        int cbase = khw * 32 + q * 8;
        #pragma unroll
        for (int j = 0; j < 8; ++j)
            o[j] = f2bf(Wh[((size_t)tap * FF + cbase + j) * G4 + n]);
    } else {
        int tap = (s - 18) * 4 + q;                  // packed x-taps; >8 -> zero pad
        #pragma unroll
        for (int j = 0; j < 8; ++j)
            o[j] = (tap < 9) ? f2bf(Wx[((size_t)tap * CINX + j) * G4 + n]) : (ushort)0;
    }
    U16 u;
    #pragma unroll
    for (int j = 0; j < 8; ++j) ((ushort*)&u)[j] = o[j];
    ((uint4*)Bp)[idx] = u.u;
}

// ---- main step kernel ----
__global__ __launch_bounds__(256, 3) void convlstm_mfma(
    const ushort* __restrict__ xbf, int t,
    const ushort* __restrict__ hS_in,     // [s8][pos][8] bf16 ([slice][pos][16])
    ushort* __restrict__ hS_out,
    float* __restrict__ cS,               // [slice][pos][16] fp32
    const ushort* __restrict__ Bp,
    const float* __restrict__ bias,
    const uint4* __restrict__ zpad,       // 64B of zeros for OOB halo reads
    float* __restrict__ out, int last)
{
    // plane p = kh*4+q holds 8 channels (s8 = kh*2+(q>>1), half = q&1) for 144 pos
    __shared__ __align__(16) ushort hplanes[8 * PSTR];   // 18.6 KB (bank-padded)
    __shared__ __align__(16) ushort xplane[144 * 8];     // 2.3 KB

    const int tid = threadIdx.x;
    const int x0 = blockIdx.x * 16, y0 = blockIdx.y * 6;
    const int bb = blockIdx.z;
    const int w = tid >> 6, lane = tid & 63, q = lane >> 4, col = lane & 15;
    const int slice = w;                              // one slice per wave

    // per-lane B pointer: fragment (s,g) at gB[s*256 + g*64]; 1KB contiguous/wave
    const uint4* gB = (const uint4*)Bp + (size_t)(slice * 21) * 256 + lane;

    // stage 8x18 halo (pos = tid < 144): 8 h-planes + 1 x-plane, 16B each
    if (tid < 144) {
        int py = tid / 18, px = tid - py * 18;
        int gy = y0 - 1 + py, gx = x0 - 1 + px;
        bool ok = (gy >= 0 && gy < HTOT && gx >= 0 && gx < WTOT);
        int gyc = gy < 0 ? 0 : (gy > HTOT - 1 ? HTOT - 1 : gy);
        int gxc = gx < 0 ? 0 : (gx > WTOT - 1 ? WTOT - 1 : gx);
        size_t gpos = ((size_t)bb * HTOT + gyc) * WTOT + gxc;
        #pragma unroll
        for (int p = 0; p < 8; ++p) {
            int s8 = (p >> 2) * 2 + ((p & 3) >> 1), half = p & 1;
            const void* src = ok
                ? (const void*)(hS_in + ((size_t)s8 * NPOS + gpos) * 16 + half * 8)
                : (const void*)zpad;
            async16(src, hplanes + p * PSTR + tid * 8);
        }
        const void* sx = ok
            ? (const void*)(xbf + ((((size_t)bb * TT + t) * HTOT + gyc) * WTOT + gxc) * CINX)
            : (const void*)zpad;
        async16(sx, xplane + tid * 8);
    }

    // B slab 0 -> regs while staging is in flight
    U16 b4[4];
    #pragma unroll
    for (int g = 0; g < 4; ++g) b4[g].u = gB[g * 64];

    floatx4 acc[6][4];
    #pragma unroll
    for (int g = 0; g < 4; ++g) {
        float bv = bias[g * 64 + slice * 16 + col];
        #pragma unroll
        for (int mt = 0; mt < 6; ++mt) acc[mt][g] = (floatx4){bv, bv, bv, bv};
    }

    __syncthreads();   // drains halo async loads; only barrier in the kernel

    // per-lane A base in LDS: plane (kh,q), pos (row j, col col+dx)
    const ushort* hA = hplanes + q * PSTR + col * 8;

    // ---- h phase: s = dx*6 + kh*3 + dy; ring-6 A window over halo rows ----
    U16 aw[6];
    #pragma unroll
    for (int dx = 0; dx < 3; ++dx) {
        #pragma unroll
        for (int kh = 0; kh < 2; ++kh) {
            #pragma unroll
            for (int j = 0; j < 6; ++j)            // prime halo rows 0..5
                aw[j].u = *(const uint4*)(hA + kh * 4 * PSTR + (j * 18 + dx) * 8);
            #pragma unroll
            for (int dy = 0; dy < 3; ++dy) {
                const int s = dx * 6 + kh * 3 + dy;
                if (dy)                             // slide: halo row 5+dy
                    aw[(5 + dy) % 6].u =
                        *(const uint4*)(hA + kh * 4 * PSTR + ((5 + dy) * 18 + dx) * 8);
                if (s) {                            // B for this step (s=0 preloaded)
                    #pragma unroll
                    for (int g = 0; g < 4; ++g) b4[g].u = gB[s * 256 + g * 64];
                }
                #pragma unroll
                for (int g = 0; g < 4; ++g)
                    #pragma unroll
                    for (int mt = 0; mt < 6; ++mt)
                        acc[mt][g] = __builtin_amdgcn_mfma_f32_16x16x32_bf16(
                            aw[(mt + dy) % 6].s, b4[g].s, acc[mt][g], 0, 0, 0);
            }
        }
    }

    // ---- x phase: s = 18,19,20; packed taps (tap = sx*4+q, B rows 0 for pad) ----
    #pragma unroll
    for (int sx = 0; sx < 3; ++sx) {
        const int s = 18 + sx;
        #pragma unroll
        for (int g = 0; g < 4; ++g) b4[g].u = gB[s * 256 + g * 64];
        int tap = sx * 4 + q; if (tap > 8) tap = 8;
        int dyq = tap / 3, dxq = tap - 3 * dyq;
        U16 a4[6];
        #pragma unroll
        for (int mt = 0; mt < 6; ++mt)
            a4[mt].u = *(const uint4*)(xplane + ((mt + dyq) * 18 + col + dxq) * 8);
        #pragma unroll
        for (int g = 0; g < 4; ++g)
            #pragma unroll
            for (int mt = 0; mt < 6; ++mt)
                acc[mt][g] = __builtin_amdgcn_mfma_f32_16x16x32_bf16(
                    a4[mt].s, b4[g].s, acc[mt][g], 0, 0, 0);
    }

    // ---- epilogue: gates fused in-register; slice-major state writes ----
    #pragma unroll
    for (int mt = 0; mt < 6; ++mt) {
        int gy = y0 + mt;
        #pragma unroll
        for (int r = 0; r < 4; ++r) {
            int gx = x0 + q * 4 + r;
            size_t gpos = ((size_t)bb * HTOT + gy) * WTOT + gx;
            size_t idx = ((size_t)slice * NPOS + gpos) * 16 + col;
            float zi = acc[mt][0][r], zf = acc[mt][1][r];
            float zg = acc[mt][2][r], zo = acc[mt][3][r];
            float cn = hsig(zf) * cS[idx] + hsig(zi) * ftanh(zg);
            cS[idx] = cn;
            float hn = hsig(zo) * ftanh(cn);
            hS_out[idx] = f2bf(hn);
            if (last) out[gpos * 64 + slice * 16 + col] = hn;
        }
    }
}

extern "C" void kernel_launch(void* const* d_in, const int* in_sizes, int n_in,
                              void* d_out, int out_size, void* d_ws, size_t ws_size,
                              hipStream_t stream) {
    const float* x  = (const float*)d_in[0];
    const float* Wx = (const float*)d_in[1];
    const float* Wh = (const float*)d_in[2];
    const float* b  = (const float*)d_in[3];

    const size_t NX = (size_t)BB * TT * HTOT * WTOT * CINX;  // 9,437,184
    const size_t NH = (size_t)NPOS * FF;                     // 4,718,592

    char* ws = (char*)d_ws;
    ushort* xbf = (ushort*)ws;                  ws += NX * 2;            // 18.9 MB
    ushort* hS0 = (ushort*)ws;                  ws += NH * 2;            //  9.4 MB
    ushort* hS1 = (ushort*)ws;                  ws += NH * 2;            //  9.4 MB
    float*  cS  = (float*)ws;                   ws += NH * 4;            // 18.9 MB
    ushort* Bp  = (ushort*)ws;                  ws += (size_t)4*21*256*16; // 344 KB
    uint4*  zpad = (uint4*)ws;                                           // 64 B zeros

    hipMemsetAsync(hS0, 0, NH * 2, stream);
    hipMemsetAsync(cS,  0, NH * 4, stream);
    hipMemsetAsync(zpad, 0, 64, stream);

    conv_x_bf16<<<(int)((NX / 4 + 255) / 256), 256, 0, stream>>>(x, xbf, (int)(NX / 4));
    prep_w<<<(4 * 21 * 256 + 255) / 256, 256, 0, stream>>>(Wx, Wh, Bp);

    dim3 grid(WTOT / 16, HTOT / 6, BB);          // 6 x 16 x 8 = 768 blocks
    for (int t = 0; t < TT; ++t) {
        const ushort* hin = (t & 1) ? hS1 : hS0;
        ushort* hout      = (t & 1) ? hS0 : hS1;
        convlstm_mfma<<<grid, 256, 0, stream>>>(xbf, t, hin, hout, cS, Bp, b, zpad,
                                                (float*)d_out, t == TT - 1);
    }
}